// Round 1
// baseline (403.313 us; speedup 1.0000x reference)
//
#include <hip/hip_runtime.h>
#include <hip/hip_bf16.h>

// Sizes (fixed by the problem)
#define B_    4
#define H_    8
#define S_    8192
#define D_    128
#define RANK_ 512
#define KTOT  1536          // IN_FEAT = 64*8 + 128*8
#define MTOT  32768         // B_*S_
#define NROWS (B_*H_*S_)    // 262144
#define C_ELEMS (MTOT*RANK_)  // 16777216

typedef __attribute__((ext_vector_type(4))) float  f32x4;
typedef __attribute__((ext_vector_type(8))) short  short8;

static __device__ __forceinline__ short f2bf(float f) {
  union { __hip_bfloat16 h; short s; } u;
  u.h = __float2bfloat16(f);
  return u.s;
}

static __device__ __forceinline__ void gload_lds16(const void* gsrc, void* ldst) {
  __builtin_amdgcn_global_load_lds(
      (const __attribute__((address_space(1))) void*)gsrc,
      (__attribute__((address_space(3))) void*)ldst, 16, 0, 0);
}

// ---------------------------------------------------------------------------
// Kernel 1: build effective B matrix (1536 x 512) in bf16 into d_ws.
//   rows j in [0,512):  h=j>>6, d=j&63 : B[j][r] = sum_e U[e][d]*R[h*64+e][r] / alpha
//   rows j in [512,1536): B[j][r] = R[j][r]
// ws layout: per GEMM K-tile kb (=j>>6, 24 tiles of 64 rows), stored as
//   [c = (j>>3)&7][n = r (512)][kk = j&7]  bf16  -> 64 KB per tile, linear
//   global_load_lds target for the GEMM.
// ---------------------------------------------------------------------------
__global__ __launch_bounds__(256) void build_b_kernel(
    const float* __restrict__ U, const float* __restrict__ R,
    const float* __restrict__ alpha, short* __restrict__ wsB)
{
  const int j0 = blockIdx.x * 8;       // 192 blocks
  const int t  = threadIdx.x;          // 0..255 -> r = t and t+256
  float vals[2][8];

  if (j0 < 512) {
    const int h   = j0 >> 6;
    const int dy0 = j0 & 63;
    const float ia = 1.0f / alpha[0];
    float acc0[8], acc1[8];
#pragma unroll
    for (int kk = 0; kk < 8; ++kk) { acc0[kk] = 0.f; acc1[kk] = 0.f; }
    for (int e = 0; e < 64; ++e) {
      const float r0 = R[(h*64 + e)*RANK_ + t];
      const float r1 = R[(h*64 + e)*RANK_ + t + 256];
#pragma unroll
      for (int kk = 0; kk < 8; ++kk) {
        const float u = U[e*64 + dy0 + kk];
        acc0[kk] += u * r0;
        acc1[kk] += u * r1;
      }
    }
#pragma unroll
    for (int kk = 0; kk < 8; ++kk) {
      vals[0][kk] = acc0[kk] * ia;
      vals[1][kk] = acc1[kk] * ia;
    }
  } else {
#pragma unroll
    for (int kk = 0; kk < 8; ++kk) {
      vals[0][kk] = R[(size_t)(j0 + kk)*RANK_ + t];
      vals[1][kk] = R[(size_t)(j0 + kk)*RANK_ + t + 256];
    }
  }

  const int kb = j0 >> 6;
  const int c  = (j0 >> 3) & 7;
  char* base = (char*)wsB + (size_t)kb*65536 + (size_t)c*8192;
#pragma unroll
  for (int half = 0; half < 2; ++half) {
    const int r = t + half*256;
    short8 o;
#pragma unroll
    for (int kk = 0; kk < 8; ++kk) o[kk] = f2bf(vals[half][kk]);
    *(short8*)(base + (size_t)r*16) = o;
  }
}

// ---------------------------------------------------------------------------
// Kernel 2: K_rope[b,h,s,e] = sum_d K[b,h,s,d<64] * U[e][d]   (f32 VALU)
// Lane e holds U row e in registers; K_x row broadcast via wave-private LDS.
// ---------------------------------------------------------------------------
__global__ __launch_bounds__(256) void rope_kernel(
    const float* __restrict__ K, const float* __restrict__ U,
    float* __restrict__ Orope)
{
  __shared__ float ks[4][64];
  const int lane = threadIdx.x & 63;
  const int wid  = threadIdx.x >> 6;

  float4 u4[16];
#pragma unroll
  for (int i = 0; i < 16; ++i)
    u4[i] = *(const float4*)&U[lane*64 + i*4];

  const int gw = blockIdx.x*4 + wid;
  const int nw = gridDim.x*4;
  for (int row = gw; row < NROWS; row += nw) {
    const float kx = K[(size_t)row*D_ + lane];   // lanes 0..63 = K_x
    ks[wid][lane] = kx;
    float acc = 0.f;
#pragma unroll
    for (int i = 0; i < 16; ++i) {
      const float4 kk = *(const float4*)&ks[wid][i*4];  // uniform broadcast read
      acc += kk.x*u4[i].x + kk.y*u4[i].y + kk.z*u4[i].z + kk.w*u4[i].w;
    }
    Orope[(size_t)row*64 + lane] = acc;
  }
}

// ---------------------------------------------------------------------------
// Kernel 3: C (32768 x 512) = A (32768 x 1536) @ Beff (1536 x 512), bf16 MFMA.
// A cols j<512: K_y (h=j>>6, d=j&63, from K[...,64+d]); j>=512: V (h,d of jj).
// BM=128, BN=512 (full N -> A read once), BK=64, 512 threads (8 waves, 2x4).
// LDS: A [c=k>>3][m][8] 16KB + B [c][n][8] 64KB, single buffer, 2 barriers.
// ---------------------------------------------------------------------------
__global__ __launch_bounds__(512, 2) void gemm_kernel(
    const float* __restrict__ Kp, const float* __restrict__ Vp,
    const short* __restrict__ wsB, float* __restrict__ C)
{
  __shared__ short A_lds[8*128*8];   // 16 KB
  __shared__ short B_lds[8*512*8];   // 64 KB

  const int tid  = threadIdx.x;
  const int lane = tid & 63;
  const int wid  = tid >> 6;
  const int wave_m = wid >> 2;       // 0..1  (64 rows each)
  const int wave_n = wid & 3;        // 0..3  (128 cols each)
  const int row0 = blockIdx.x * 128;

  // A-staging role: thread covers row r, cols q*16..q*16+15 of the K-tile
  const int r = tid >> 2;            // 0..127
  const int q = tid & 3;             // 0..3
  const int m_stage = row0 + r;
  const int b = m_stage >> 13;
  const int s = m_stage & 8191;
  const size_t rowbase = ((size_t)(b*H_))*S_*D_ + (size_t)s*D_;  // h=0 base

  // MFMA fragment addressing
  const int am   = wave_m*64  + (lane & 15);
  const int bn   = wave_n*128 + (lane & 15);
  const int kblk = lane >> 4;        // 0..3

  f32x4 acc[4][8];
#pragma unroll
  for (int mi = 0; mi < 4; ++mi)
#pragma unroll
    for (int ni = 0; ni < 8; ++ni)
      acc[mi][ni] = (f32x4){0.f, 0.f, 0.f, 0.f};

  for (int kb = 0; kb < 24; ++kb) {
    // ---- B stage: linear async copy of pre-arranged 64 KB tile ----
    {
      const char* gsrc = (const char*)wsB + (size_t)kb*65536 + wid*8192 + lane*16;
      char*       ldst = (char*)B_lds     +                  wid*8192 + lane*16;
#pragma unroll
      for (int i = 0; i < 8; ++i)
        gload_lds16(gsrc + i*1024, ldst + i*1024);
    }
    // ---- A stage: f32 load -> bf16 -> LDS [c][m][8] ----
    {
      const int j0 = kb*64;
      const float* asrc;
      if (j0 < 512) {
        const int h = j0 >> 6;
        asrc = Kp + rowbase + (size_t)h*S_*D_ + 64;
      } else {
        const int jj = j0 - 512;
        const int h  = jj >> 7;
        asrc = Vp + rowbase + (size_t)h*S_*D_ + (jj & 127);
      }
      const float* tsrc = asrc + q*16;
      const float4 l0 = *(const float4*)(tsrc +  0);
      const float4 l1 = *(const float4*)(tsrc +  4);
      const float4 l2 = *(const float4*)(tsrc +  8);
      const float4 l3 = *(const float4*)(tsrc + 12);
      short8 c0, c1;
      c0[0]=f2bf(l0.x); c0[1]=f2bf(l0.y); c0[2]=f2bf(l0.z); c0[3]=f2bf(l0.w);
      c0[4]=f2bf(l1.x); c0[5]=f2bf(l1.y); c0[6]=f2bf(l1.z); c0[7]=f2bf(l1.w);
      c1[0]=f2bf(l2.x); c1[1]=f2bf(l2.y); c1[2]=f2bf(l2.z); c1[3]=f2bf(l2.w);
      c1[4]=f2bf(l3.x); c1[5]=f2bf(l3.y); c1[6]=f2bf(l3.z); c1[7]=f2bf(l3.w);
      *(short8*)((char*)A_lds + (size_t)(2*q  )*2048 + (size_t)r*16) = c0;
      *(short8*)((char*)A_lds + (size_t)(2*q+1)*2048 + (size_t)r*16) = c1;
    }
    __syncthreads();   // drains vmcnt (B in LDS) + lgkm (A writes)

    // ---- compute: 64 MFMA per wave ----
#pragma unroll
    for (int ks = 0; ks < 2; ++ks) {
      const int cA = ks*4 + kblk;
      short8 af[4], bfr[8];
#pragma unroll
      for (int mi = 0; mi < 4; ++mi)
        af[mi] = *(const short8*)((const char*)A_lds + cA*2048 + (size_t)(am + mi*16)*16);
#pragma unroll
      for (int ni = 0; ni < 8; ++ni)
        bfr[ni] = *(const short8*)((const char*)B_lds + cA*8192 + (size_t)(bn + ni*16)*16);
#pragma unroll
      for (int mi = 0; mi < 4; ++mi)
#pragma unroll
        for (int ni = 0; ni < 8; ++ni)
          acc[mi][ni] = __builtin_amdgcn_mfma_f32_16x16x32_bf16(
              af[mi], bfr[ni], acc[mi][ni], 0, 0, 0);
    }
    __syncthreads();   // LDS reusable next iteration
  }

  // ---- epilogue: C/D layout col=lane&15, row=(lane>>4)*4+reg ----
  const int erow = (lane >> 4)*4;
#pragma unroll
  for (int mi = 0; mi < 4; ++mi)
#pragma unroll
    for (int ni = 0; ni < 8; ++ni)
#pragma unroll
      for (int rg = 0; rg < 4; ++rg) {
        const int row = row0 + wave_m*64 + mi*16 + erow + rg;
        const int col = wave_n*128 + ni*16 + (lane & 15);
        C[(size_t)row*RANK_ + col] = acc[mi][ni][rg];
      }
}

extern "C" void kernel_launch(void* const* d_in, const int* in_sizes, int n_in,
                              void* d_out, int out_size, void* d_ws, size_t ws_size,
                              hipStream_t stream) {
  const float* K     = (const float*)d_in[0];
  const float* V     = (const float*)d_in[1];
  const float* U     = (const float*)d_in[2];
  const float* R     = (const float*)d_in[3];
  const float* alpha = (const float*)d_in[4];
  float* C     = (float*)d_out;             // C_kv: 16777216 f32
  float* Orope = (float*)d_out + C_ELEMS;   // K_rope: 16777216 f32
  short* wsB   = (short*)d_ws;              // needs 1.5 MB scratch

  build_b_kernel<<<192,  256, 0, stream>>>(U, R, alpha, wsB);
  rope_kernel   <<<2048, 256, 0, stream>>>(K, U, Orope);
  gemm_kernel   <<<256,  512, 0, stream>>>(K, V, wsB, C);
}

// Round 2
// 381.579 us; speedup vs baseline: 1.0570x; 1.0570x over previous
//
#include <hip/hip_runtime.h>
#include <hip/hip_bf16.h>

// Sizes (fixed by the problem)
#define B_    4
#define H_    8
#define S_    8192
#define D_    128
#define RANK_ 512
#define MTOT  32768         // B_*S_
#define NROWS (B_*H_*S_)    // 262144
#define C_ELEMS (MTOT*RANK_)  // 16777216

typedef __attribute__((ext_vector_type(4))) float  f32x4;
typedef __attribute__((ext_vector_type(8))) short  short8;

static __device__ __forceinline__ short f2bf(float f) {
  union { __hip_bfloat16 h; short s; } u;
  u.h = __float2bfloat16(f);
  return u.s;
}

static __device__ __forceinline__ void gload_lds16(const void* gsrc, void* ldst) {
  __builtin_amdgcn_global_load_lds(
      (const __attribute__((address_space(1))) void*)gsrc,
      (__attribute__((address_space(3))) void*)ldst, 16, 0, 0);
}

// ---------------------------------------------------------------------------
// Kernel 1: build effective B matrix (1536 x 512) bf16 into d_ws.
//   rows j<512 (K_nope部):  B[j][r] = sum_e U[e][j&63]*R[(j>>6)*64+e][r] / alpha
//   rows j>=512 (V part):   B[j][r] = R[j][r]
// Layout: per K-tile kb=j>>6 (24 tiles), [c=(j>>3)&7][n=r][kk=j&7] bf16 =
// 64 KB/tile, linear global_load_lds source for the GEMM.
// ---------------------------------------------------------------------------
__global__ __launch_bounds__(256) void build_b_kernel(
    const float* __restrict__ U, const float* __restrict__ R,
    const float* __restrict__ alpha, short* __restrict__ wsB)
{
  const int j0 = blockIdx.x * 8;       // 192 blocks
  const int t  = threadIdx.x;          // r = t and t+256
  float vals[2][8];

  if (j0 < 512) {
    const int h   = j0 >> 6;
    const int dy0 = j0 & 63;
    const float ia = 1.0f / alpha[0];
    float acc0[8], acc1[8];
#pragma unroll
    for (int kk = 0; kk < 8; ++kk) { acc0[kk] = 0.f; acc1[kk] = 0.f; }
    for (int e = 0; e < 64; ++e) {
      const float r0 = R[(h*64 + e)*RANK_ + t];
      const float r1 = R[(h*64 + e)*RANK_ + t + 256];
#pragma unroll
      for (int kk = 0; kk < 8; ++kk) {
        const float u = U[e*64 + dy0 + kk];
        acc0[kk] += u * r0;
        acc1[kk] += u * r1;
      }
    }
#pragma unroll
    for (int kk = 0; kk < 8; ++kk) {
      vals[0][kk] = acc0[kk] * ia;
      vals[1][kk] = acc1[kk] * ia;
    }
  } else {
#pragma unroll
    for (int kk = 0; kk < 8; ++kk) {
      vals[0][kk] = R[(size_t)(j0 + kk)*RANK_ + t];
      vals[1][kk] = R[(size_t)(j0 + kk)*RANK_ + t + 256];
    }
  }

  const int kb = j0 >> 6;
  const int c  = (j0 >> 3) & 7;
  char* base = (char*)wsB + (size_t)kb*65536 + (size_t)c*8192;
#pragma unroll
  for (int half = 0; half < 2; ++half) {
    const int r = t + half*256;
    short8 o;
#pragma unroll
    for (int kk = 0; kk < 8; ++kk) o[kk] = f2bf(vals[half][kk]);
    *(short8*)(base + (size_t)r*16) = o;
  }
}

// ---------------------------------------------------------------------------
// Kernel 2: K_rope[b,h,s,e] = sum_d K[b,h,s,d<64] * U[e][d]   (f32 VALU)
// Lane e holds U row e; 2 rows per iteration for 2 loads in flight.
// ---------------------------------------------------------------------------
__global__ __launch_bounds__(256) void rope_kernel(
    const float* __restrict__ K, const float* __restrict__ U,
    float* __restrict__ Orope)
{
  __shared__ float ks[4][2][64];
  const int lane = threadIdx.x & 63;
  const int wid  = threadIdx.x >> 6;

  float4 u4[16];
#pragma unroll
  for (int i = 0; i < 16; ++i)
    u4[i] = *(const float4*)&U[lane*64 + i*4];

  const int gw = blockIdx.x*4 + wid;
  const int nw = gridDim.x*4;
  for (int pair = gw; pair < NROWS/2; pair += nw) {
    const int row0 = pair*2;
    const float k0 = K[(size_t)row0*D_ + lane];
    const float k1 = K[(size_t)row0*D_ + D_ + lane];
    ks[wid][0][lane] = k0;
    ks[wid][1][lane] = k1;
    float a0 = 0.f, a1 = 0.f;
#pragma unroll
    for (int i = 0; i < 16; ++i) {
      const float4 c0 = *(const float4*)&ks[wid][0][i*4];
      const float4 c1 = *(const float4*)&ks[wid][1][i*4];
      a0 += c0.x*u4[i].x + c0.y*u4[i].y + c0.z*u4[i].z + c0.w*u4[i].w;
      a1 += c1.x*u4[i].x + c1.y*u4[i].y + c1.z*u4[i].z + c1.w*u4[i].w;
    }
    Orope[(size_t)row0*64 + lane]      = a0;
    Orope[(size_t)row0*64 + 64 + lane] = a1;
  }
}

// ---------------------------------------------------------------------------
// Kernel 3: C (32768x512) = A (32768x1536) @ Beff (1536x512), bf16 MFMA.
// BM=128, BN=512 (full N -> A read once), BK=64, 512 threads (8 waves 2x4).
// Pipeline: B double-buffered via global_load_lds issued 1 tile ahead;
// A reg-prefetched (f32) 1 tile ahead, cvt+ds_write after barrier1.
// barrier2 = raw s_barrier + lgkmcnt(0) so B(kb+2) DMA stays in flight.
// ---------------------------------------------------------------------------
__global__ __launch_bounds__(512, 2) void gemm_kernel(
    const float* __restrict__ Kp, const float* __restrict__ Vp,
    const short* __restrict__ wsB, float* __restrict__ C)
{
  __shared__ short B_lds[2][8*512*8];  // 2 x 64 KB
  __shared__ short A_lds[8*128*8];     // 16 KB   (total 144 KB)

  const int tid  = threadIdx.x;
  const int lane = tid & 63;
  const int wid  = tid >> 6;
  const int wave_m = wid >> 2;        // 0..1
  const int wave_n = wid & 3;         // 0..3
  const int row0 = blockIdx.x * 128;

  // A-staging role: thread covers row r, cols q*16..q*16+15 of the K-tile
  const int r = tid >> 2;             // 0..127
  const int q = tid & 3;              // 0..3
  const int m_stage = row0 + r;
  const int b = m_stage >> 13;
  const int s = m_stage & 8191;
  const size_t rowbase = ((size_t)(b*H_))*S_*D_ + (size_t)s*D_;  // h=0 base

  // MFMA fragment addressing
  const int am   = wave_m*64  + (lane & 15);
  const int bn   = wave_n*128 + (lane & 15);
  const int kblk = lane >> 4;

  f32x4 acc[4][8];
#pragma unroll
  for (int mi = 0; mi < 4; ++mi)
#pragma unroll
    for (int ni = 0; ni < 8; ++ni)
      acc[mi][ni] = (f32x4){0.f, 0.f, 0.f, 0.f};

  f32x4 st[4];   // A prefetch registers (16 f32)

  auto issueA = [&](int kb) {
    const float* asrc;
    if (kb < 8) {
      asrc = Kp + rowbase + (size_t)kb*S_*D_ + 64;          // K_y of head kb
    } else {
      const int jj = (kb - 8) * 64;
      asrc = Vp + rowbase + (size_t)(jj >> 7)*S_*D_ + (jj & 127);
    }
    const float* tsrc = asrc + q*16;
    st[0] = *(const f32x4*)(tsrc +  0);
    st[1] = *(const f32x4*)(tsrc +  4);
    st[2] = *(const f32x4*)(tsrc +  8);
    st[3] = *(const f32x4*)(tsrc + 12);
  };

  auto writeA = [&]() {
    short8 c0, c1;
#pragma unroll
    for (int i = 0; i < 4; ++i) { c0[i]   = f2bf(st[0][i]); c0[4+i] = f2bf(st[1][i]); }
#pragma unroll
    for (int i = 0; i < 4; ++i) { c1[i]   = f2bf(st[2][i]); c1[4+i] = f2bf(st[3][i]); }
    *(short8*)((char*)A_lds + (size_t)(2*q  )*2048 + (size_t)r*16) = c0;
    *(short8*)((char*)A_lds + (size_t)(2*q+1)*2048 + (size_t)r*16) = c1;
  };

  auto issueB = [&](int t) {
    const char* gsrc = (const char*)wsB + (size_t)t*65536 + wid*8192 + lane*16;
    char*       ldst = (char*)B_lds[t & 1]               + wid*8192 + lane*16;
#pragma unroll
    for (int i = 0; i < 8; ++i)
      gload_lds16(gsrc + i*1024, ldst + i*1024);
  };

  // ---- prologue ----
  issueB(0);
  issueB(1);
  issueA(0);
  writeA();
  __syncthreads();   // drains B0 (+B1, A0 regs) and A ds_writes

  for (int kb = 0; kb < 24; ++kb) {
    if (kb + 1 < 24) issueA(kb + 1);   // HBM latency hides under compute

    // ---- compute: 64 MFMA per wave from B_lds[kb&1], A_lds ----
    const short* Bcur = B_lds[kb & 1];
#pragma unroll
    for (int ks = 0; ks < 2; ++ks) {
      const int cA = ks*4 + kblk;
      short8 af[4], bfr[8];
#pragma unroll
      for (int mi = 0; mi < 4; ++mi)
        af[mi] = *(const short8*)((const char*)A_lds + cA*2048 + (size_t)(am + mi*16)*16);
#pragma unroll
      for (int ni = 0; ni < 8; ++ni)
        bfr[ni] = *(const short8*)((const char*)Bcur + cA*8192 + (size_t)(bn + ni*16)*16);
#pragma unroll
      for (int mi = 0; mi < 4; ++mi)
#pragma unroll
        for (int ni = 0; ni < 8; ++ni)
          acc[mi][ni] = __builtin_amdgcn_mfma_f32_16x16x32_bf16(
              af[mi], bfr[ni], acc[mi][ni], 0, 0, 0);
    }

    if (kb + 1 < 24) {
      // barrier1: all waves done reading A_lds & B_lds[kb&1]; implicit
      // vmcnt(0) drains B(kb+1) (streamed during compute) + A(kb+1) regs.
      __syncthreads();
      if (kb + 2 < 24) issueB(kb + 2);   // into B_lds[kb&1], just freed
      writeA();                           // cvt + ds_write A(kb+1)
      // barrier2: LDS writes visible, but keep B(kb+2) DMA in flight.
      asm volatile("s_waitcnt lgkmcnt(0)" ::: "memory");
      __builtin_amdgcn_sched_barrier(0);
      __builtin_amdgcn_s_barrier();
      __builtin_amdgcn_sched_barrier(0);
    }
  }

  // ---- epilogue: C/D layout col=lane&15, row=(lane>>4)*4+reg ----
  const int erow = (lane >> 4)*4;
#pragma unroll
  for (int mi = 0; mi < 4; ++mi)
#pragma unroll
    for (int ni = 0; ni < 8; ++ni)
#pragma unroll
      for (int rg = 0; rg < 4; ++rg) {
        const int row = row0 + wave_m*64 + mi*16 + erow + rg;
        const int col = wave_n*128 + ni*16 + (lane & 15);
        C[(size_t)row*RANK_ + col] = acc[mi][ni][rg];
      }
}

extern "C" void kernel_launch(void* const* d_in, const int* in_sizes, int n_in,
                              void* d_out, int out_size, void* d_ws, size_t ws_size,
                              hipStream_t stream) {
  const float* K     = (const float*)d_in[0];
  const float* V     = (const float*)d_in[1];
  const float* U     = (const float*)d_in[2];
  const float* R     = (const float*)d_in[3];
  const float* alpha = (const float*)d_in[4];
  float* Cv    = (float*)d_out;             // C_kv: 16777216 f32
  float* Orope = (float*)d_out + C_ELEMS;   // K_rope: 16777216 f32
  short* wsB   = (short*)d_ws;              // 1.5 MB scratch

  build_b_kernel<<<192,  256, 0, stream>>>(U, R, alpha, wsB);
  rope_kernel   <<<2048, 256, 0, stream>>>(K, U, Orope);
  gemm_kernel   <<<256,  512, 0, stream>>>(K, V, wsB, Cv);
}